// Round 4
// baseline (1154.564 us; speedup 1.0000x reference)
//
#include <hip/hip_runtime.h>
#include <hip/hip_bf16.h>

#define NF 40960
#define BATCH 2048
#define CAP 512

__device__ __forceinline__ float clip01(float v) {
    return fminf(fmaxf(v, 0.0f), 1.0f);
}

// Single fused kernel: sparse scan (memory-roofline, ~205us for 713MB reads)
// + direct column gather from ft_w (L3-resident, hidden under read shadow)
// + MLP tail. One launch, no transpose, no workspace traffic.
__global__ __launch_bounds__(256) void nnue_fused(
    const float* __restrict__ wf, const float* __restrict__ bfeat,
    const float* __restrict__ stm, const float* __restrict__ ft_w,
    const float* __restrict__ ft_b,
    const float* __restrict__ l1_w, const float* __restrict__ l1_b,
    const float* __restrict__ l2_w, const float* __restrict__ l2_b,
    const float* __restrict__ l3_w, const float* __restrict__ l3_b,
    float* __restrict__ out)
{
    __shared__ int idxW[CAP];
    __shared__ int idxB[CAP];
    __shared__ int nW, nB;
    __shared__ float xsh[512];
    __shared__ float red[32][9];   // odd stride: conflict-free
    __shared__ float ysh[32], zsh[32];

    const int pos = blockIdx.x;
    const int t = threadIdx.x;

    if (t == 0) { nW = 0; nB = 0; }
    __syncthreads();

    // ---- phase 1: scan both feature rows (coalesced float4), compact nonzeros.
    // This phase IS the kernel's cost: 671MB of reads at the ~3.5TB/s read
    // ceiling. (R1-R3 showed inner-loop restructuring does not move it.)
    const float4* wf4 = (const float4*)(wf + (size_t)pos * NF);
    const float4* bf4 = (const float4*)(bfeat + (size_t)pos * NF);
    #pragma unroll 4
    for (int i = t; i < NF / 4; i += 256) {
        float4 v = wf4[i];
        if (v.x + v.y + v.z + v.w != 0.0f) {   // features are exactly 0/1
            if (v.x != 0.0f) { int p = atomicAdd(&nW, 1); if (p < CAP) idxW[p] = 4 * i + 0; }
            if (v.y != 0.0f) { int p = atomicAdd(&nW, 1); if (p < CAP) idxW[p] = 4 * i + 1; }
            if (v.z != 0.0f) { int p = atomicAdd(&nW, 1); if (p < CAP) idxW[p] = 4 * i + 2; }
            if (v.w != 0.0f) { int p = atomicAdd(&nW, 1); if (p < CAP) idxW[p] = 4 * i + 3; }
        }
        float4 u = bf4[i];
        if (u.x + u.y + u.z + u.w != 0.0f) {
            if (u.x != 0.0f) { int p = atomicAdd(&nB, 1); if (p < CAP) idxB[p] = 4 * i + 0; }
            if (u.y != 0.0f) { int p = atomicAdd(&nB, 1); if (p < CAP) idxB[p] = 4 * i + 1; }
            if (u.z != 0.0f) { int p = atomicAdd(&nB, 1); if (p < CAP) idxB[p] = 4 * i + 2; }
            if (u.w != 0.0f) { int p = atomicAdd(&nB, 1); if (p < CAP) idxB[p] = 4 * i + 3; }
        }
    }
    __syncthreads();

    const int cw = min(nW, CAP);
    const int cb = min(nB, CAP);

    // ---- phase 2: direct gather from ft_w; thread t owns channel m = t.
    // Column-strided (uncoalesced) but ft_w is 42MB -> L3-resident; costs
    // L3 latency only, overlapped with other blocks' scan streams.
    {
        const float* row = ft_w + (size_t)t * NF;
        float a0 = 0.0f, a1 = 0.0f, b0 = 0.0f, b1 = 0.0f;
        int j = 0;
        for (; j + 2 <= cw; j += 2) { a0 += row[idxW[j]]; a1 += row[idxW[j + 1]]; }
        if (j < cw) a0 += row[idxW[j]];
        j = 0;
        for (; j + 2 <= cb; j += 2) { b0 += row[idxB[j]]; b1 += row[idxB[j + 1]]; }
        if (j < cb) b0 += row[idxB[j]];

        const float bias = ft_b[t];
        const float accW = bias + a0 + a1;
        const float accB = bias + b0 + b1;

        // ---- stm perspective select + clip -> x[512]
        const float s = stm[pos];
        xsh[t]       = clip01(s * accW + (1.0f - s) * accB);
        xsh[256 + t] = clip01(s * accB + (1.0f - s) * accW);
    }
    __syncthreads();

    // ---- L1: y[n] = clip(sum_512 x[j]*l1_w[n][j] + b, 0, 1)
    {
        const int n = t & 31;
        const int c = t >> 5;
        const float* w1 = l1_w + (size_t)n * 512 + c * 64;
        const float* xx = xsh + c * 64;
        float p = 0.0f;
        #pragma unroll
        for (int j = 0; j < 64; ++j) p += xx[j] * w1[j];
        red[n][c] = p;
    }
    __syncthreads();
    if (t < 32) {
        float v = l1_b[t];
        #pragma unroll
        for (int c = 0; c < 8; ++c) v += red[t][c];
        ysh[t] = clip01(v);
    }
    __syncthreads();

    // ---- L2: z[k] = clip(sum_32 y[n]*l2_w[k][n] + b, 0, 1)
    if (t < 32) {
        float v = l2_b[t];
        const float* w2 = l2_w + t * 32;
        #pragma unroll
        for (int j = 0; j < 32; ++j) v += ysh[j] * w2[j];
        zsh[t] = clip01(v);
    }
    __syncthreads();

    // ---- L3 + output map
    if (t == 0) {
        float v = l3_b[0];
        #pragma unroll
        for (int j = 0; j < 32; ++j) v += zsh[j] * l3_w[j];
        v = clip01(v);
        out[pos] = (v - 0.5f) * 20000.0f;
    }
}

extern "C" void kernel_launch(void* const* d_in, const int* in_sizes, int n_in,
                              void* d_out, int out_size, void* d_ws, size_t ws_size,
                              hipStream_t stream) {
    const float* wf    = (const float*)d_in[0];
    const float* bfeat = (const float*)d_in[1];
    const float* stm   = (const float*)d_in[2];
    const float* ft_w  = (const float*)d_in[3];
    const float* ft_b  = (const float*)d_in[4];
    const float* l1_w  = (const float*)d_in[5];
    const float* l1_b  = (const float*)d_in[6];
    const float* l2_w  = (const float*)d_in[7];
    const float* l2_b  = (const float*)d_in[8];
    const float* l3_w  = (const float*)d_in[9];
    const float* l3_b  = (const float*)d_in[10];
    float* out = (float*)d_out;

    nnue_fused<<<BATCH, 256, 0, stream>>>(
        wf, bfeat, stm, ft_w, ft_b,
        l1_w, l1_b, l2_w, l2_b, l3_w, l3_b, out);
}

// Round 5
// 690.334 us; speedup vs baseline: 1.6725x; 1.6725x over previous
//
#include <hip/hip_runtime.h>
#include <hip/hip_bf16.h>
#include <hip/hip_cooperative_groups.h>

namespace cg = cooperative_groups;

#define NF 40960
#define MD 256
#define BATCH 2048
#define CAP 512
#define NTILE ((NF / 64) * (MD / 64))   // 2560 64x64 tiles

typedef float vf4 __attribute__((ext_vector_type(4)));

__device__ __forceinline__ float clip01(float v) {
    return fminf(fmaxf(v, 0.0f), 1.0f);
}

struct ScanSmem {
    int idxW[CAP], idxB[CAP];
    int nW, nB;
    float xsh[512];
    float red[32][9];
    float ysh[32], zsh[32];
};
union Smem {
    float tile[64][65];   // 16.64 KB (transpose phase)
    ScanSmem s;           // 7.56 KB (scan/MLP phase)
};

// ---- verified R1 scan: compact nonzero indices of one position (both colors)
__device__ __forceinline__ void scan_pos(ScanSmem& s, int t, int pos,
    const float* __restrict__ wf, const float* __restrict__ bfeat)
{
    if (t == 0) { s.nW = 0; s.nB = 0; }
    __syncthreads();
    const vf4* wf4 = (const vf4*)(wf + (size_t)pos * NF);
    const vf4* bf4 = (const vf4*)(bfeat + (size_t)pos * NF);
    #pragma unroll 4
    for (int i = t; i < NF / 4; i += 256) {
        vf4 v = __builtin_nontemporal_load(wf4 + i);   // zero-reuse stream
        if (v.x + v.y + v.z + v.w != 0.0f) {           // features are exactly 0/1
            if (v.x != 0.0f) { int p = atomicAdd(&s.nW, 1); if (p < CAP) s.idxW[p] = 4 * i;     }
            if (v.y != 0.0f) { int p = atomicAdd(&s.nW, 1); if (p < CAP) s.idxW[p] = 4 * i + 1; }
            if (v.z != 0.0f) { int p = atomicAdd(&s.nW, 1); if (p < CAP) s.idxW[p] = 4 * i + 2; }
            if (v.w != 0.0f) { int p = atomicAdd(&s.nW, 1); if (p < CAP) s.idxW[p] = 4 * i + 3; }
        }
        vf4 u = __builtin_nontemporal_load(bf4 + i);
        if (u.x + u.y + u.z + u.w != 0.0f) {
            if (u.x != 0.0f) { int p = atomicAdd(&s.nB, 1); if (p < CAP) s.idxB[p] = 4 * i;     }
            if (u.y != 0.0f) { int p = atomicAdd(&s.nB, 1); if (p < CAP) s.idxB[p] = 4 * i + 1; }
            if (u.z != 0.0f) { int p = atomicAdd(&s.nB, 1); if (p < CAP) s.idxB[p] = 4 * i + 2; }
            if (u.w != 0.0f) { int p = atomicAdd(&s.nB, 1); if (p < CAP) s.idxB[p] = 4 * i + 3; }
        }
    }
    __syncthreads();
}

// ---- verified R1 gather (transposed or fallback) + MLP tail
__device__ __forceinline__ void gather_tail(ScanSmem& s, int t, int pos,
    const float* __restrict__ gt, int transposed,
    const float* __restrict__ ft_b, const float* __restrict__ stm,
    const float* __restrict__ l1_w, const float* __restrict__ l1_b,
    const float* __restrict__ l2_w, const float* __restrict__ l2_b,
    const float* __restrict__ l3_w, const float* __restrict__ l3_b,
    float* __restrict__ out)
{
    const int cw = min(s.nW, CAP);
    const int cb = min(s.nB, CAP);

    float accW = ft_b[t];
    float accB = ft_b[t];
    if (transposed) {   // thread t owns channel m=t; 256B/wave contiguous rows
        for (int j = 0; j < cw; ++j) accW += gt[(size_t)s.idxW[j] * MD + t];
        for (int j = 0; j < cb; ++j) accB += gt[(size_t)s.idxB[j] * MD + t];
    } else {            // slow correct fallback (strided)
        const float* row = gt + (size_t)t * NF;
        for (int j = 0; j < cw; ++j) accW += row[s.idxW[j]];
        for (int j = 0; j < cb; ++j) accB += row[s.idxB[j]];
    }

    const float sv = stm[pos];
    s.xsh[t]       = clip01(sv * accW + (1.0f - sv) * accB);
    s.xsh[256 + t] = clip01(sv * accB + (1.0f - sv) * accW);
    __syncthreads();

    {   // L1: n = t&31 (broadcast reads), chunk c = t>>5
        const int n = t & 31;
        const int c = t >> 5;
        const float* w1 = l1_w + (size_t)n * 512 + c * 64;
        const float* xx = s.xsh + c * 64;
        float p = 0.0f;
        #pragma unroll
        for (int j = 0; j < 64; ++j) p += xx[j] * w1[j];
        s.red[n][c] = p;
    }
    __syncthreads();
    if (t < 32) {
        float v = l1_b[t];
        #pragma unroll
        for (int c = 0; c < 8; ++c) v += s.red[t][c];
        s.ysh[t] = clip01(v);
    }
    __syncthreads();
    if (t < 32) {
        float v = l2_b[t];
        const float* w2 = l2_w + t * 32;
        #pragma unroll
        for (int j = 0; j < 32; ++j) v += s.ysh[j] * w2[j];
        s.zsh[t] = clip01(v);
    }
    __syncthreads();
    if (t == 0) {
        float v = l3_b[0];
        #pragma unroll
        for (int j = 0; j < 32; ++j) v += s.zsh[j] * l3_w[j];
        out[pos] = (clip01(v) - 0.5f) * 20000.0f;
    }
}

// ---------------------------------------------------------------------------
// Cooperative single-launch: transpose share -> scan -> grid sync -> gather+MLP.
// 2048 blocks @ 8/CU are guaranteed co-resident by the cooperative launch, so
// the grid barrier is safe; transpose traffic overlaps the scan's read stream.
// ---------------------------------------------------------------------------
__global__ __launch_bounds__(256, 8) void nnue_coop(
    const float* __restrict__ wf, const float* __restrict__ bfeat,
    const float* __restrict__ stm, const float* __restrict__ ft_w,
    const float* __restrict__ ft_b,
    const float* __restrict__ l1_w, const float* __restrict__ l1_b,
    const float* __restrict__ l2_w, const float* __restrict__ l2_b,
    const float* __restrict__ l3_w, const float* __restrict__ l3_b,
    float* __restrict__ out, float* __restrict__ ftT)
{
    __shared__ Smem u;
    const int b = blockIdx.x;
    const int t = threadIdx.x;

    // phase A: this block's transpose share (1 or 2 tiles)
    for (int tl = b; tl < NTILE; tl += BATCH) {
        const int f0 = (tl % (NF / 64)) * 64;
        const int m0 = (tl / (NF / 64)) * 64;
        const int tx = t & 63;
        const int ty = t >> 6;
        #pragma unroll
        for (int r = ty; r < 64; r += 4)
            u.tile[r][tx] = ft_w[(size_t)(m0 + r) * NF + f0 + tx];
        __syncthreads();
        #pragma unroll
        for (int r = ty; r < 64; r += 4)
            ftT[(size_t)(f0 + r) * MD + m0 + tx] = u.tile[tx][r];
        __syncthreads();
    }

    // phase B: scan own position (~200us of streaming; hides everything)
    scan_pos(u.s, t, b, wf, bfeat);

    // phase C: wait for all transpose shares, then gather from ftT
    __threadfence();
    cg::this_grid().sync();
    __threadfence();

    gather_tail(u.s, t, b, ftT, 1, ft_b, stm,
                l1_w, l1_b, l2_w, l2_b, l3_w, l3_b, out);
}

// ---------------------------------------------------------------------------
// Fallback path (verified R1): separate transpose + monolithic kernel.
// ---------------------------------------------------------------------------
__global__ __launch_bounds__(256) void transpose_ft(const float* __restrict__ in,
                                                    float* __restrict__ outT) {
    __shared__ float tile[64][65];
    const int b = blockIdx.x;
    const int f0 = (b % (NF / 64)) * 64;
    const int m0 = (b / (NF / 64)) * 64;
    const int tx = threadIdx.x & 63;
    const int ty = threadIdx.x >> 6;
    #pragma unroll
    for (int r = ty; r < 64; r += 4)
        tile[r][tx] = in[(size_t)(m0 + r) * NF + f0 + tx];
    __syncthreads();
    #pragma unroll
    for (int r = ty; r < 64; r += 4)
        outT[(size_t)(f0 + r) * MD + m0 + tx] = tile[tx][r];
}

__global__ __launch_bounds__(256) void nnue_plain(
    const float* __restrict__ wf, const float* __restrict__ bfeat,
    const float* __restrict__ stm, const float* __restrict__ gt,
    const float* __restrict__ ft_b,
    const float* __restrict__ l1_w, const float* __restrict__ l1_b,
    const float* __restrict__ l2_w, const float* __restrict__ l2_b,
    const float* __restrict__ l3_w, const float* __restrict__ l3_b,
    float* __restrict__ out, int transposed)
{
    __shared__ Smem u;
    const int pos = blockIdx.x;
    const int t = threadIdx.x;
    scan_pos(u.s, t, pos, wf, bfeat);
    gather_tail(u.s, t, pos, gt, transposed, ft_b, stm,
                l1_w, l1_b, l2_w, l2_b, l3_w, l3_b, out);
}

extern "C" void kernel_launch(void* const* d_in, const int* in_sizes, int n_in,
                              void* d_out, int out_size, void* d_ws, size_t ws_size,
                              hipStream_t stream) {
    const float* wf    = (const float*)d_in[0];
    const float* bfeat = (const float*)d_in[1];
    const float* stm   = (const float*)d_in[2];
    const float* ft_w  = (const float*)d_in[3];
    const float* ft_b  = (const float*)d_in[4];
    const float* l1_w  = (const float*)d_in[5];
    const float* l1_b  = (const float*)d_in[6];
    const float* l2_w  = (const float*)d_in[7];
    const float* l2_b  = (const float*)d_in[8];
    const float* l3_w  = (const float*)d_in[9];
    const float* l3_b  = (const float*)d_in[10];
    float* out = (float*)d_out;

    float* ftT = (float*)d_ws;
    const size_t needT = (size_t)NF * MD * sizeof(float);
    const bool haveWs = ws_size >= needT;

    if (haveWs) {
        // host-side queries only (no stream ops) -> graph-capture safe
        int dev = 0, coopOK = 0, numCU = 0, maxBlk = 0;
        hipGetDevice(&dev);
        hipDeviceGetAttribute(&coopOK, hipDeviceAttributeCooperativeLaunch, dev);
        hipDeviceGetAttribute(&numCU, hipDeviceAttributeMultiprocessorCount, dev);
        hipOccupancyMaxActiveBlocksPerMultiprocessor(&maxBlk, nnue_coop, 256, 0);
        if (coopOK && (long)maxBlk * numCU >= BATCH) {
            void* args[] = {
                (void*)&wf, (void*)&bfeat, (void*)&stm, (void*)&ft_w, (void*)&ft_b,
                (void*)&l1_w, (void*)&l1_b, (void*)&l2_w, (void*)&l2_b,
                (void*)&l3_w, (void*)&l3_b, (void*)&out, (void*)&ftT };
            hipError_t e = hipLaunchCooperativeKernel(
                (const void*)nnue_coop, dim3(BATCH), dim3(256), args, 0, stream);
            if (e == hipSuccess) return;
        }
    }

    // fallback: verified two-kernel path
    if (haveWs) {
        transpose_ft<<<NTILE, 256, 0, stream>>>(ft_w, ftT);
        nnue_plain<<<BATCH, 256, 0, stream>>>(
            wf, bfeat, stm, ftT, ft_b,
            l1_w, l1_b, l2_w, l2_b, l3_w, l3_b, out, 1);
    } else {
        nnue_plain<<<BATCH, 256, 0, stream>>>(
            wf, bfeat, stm, ft_w, ft_b,
            l1_w, l1_b, l2_w, l2_b, l3_w, l3_b, out, 0);
    }
}